// Round 9
// baseline (112.954 us; speedup 1.0000x reference)
//
#include <hip/hip_runtime.h>

// B=8, H=W=256, single channel. Output: one fp32 scalar (composite loss).
#define HW_ELEMS 65536
#define BIGD 1e4f
#define EPSL 1e-8f
#define NBLK 2048   // one block per (b, y) row

__device__ __forceinline__ float waveSum(float v) {
  #pragma unroll
  for (int off = 32; off > 0; off >>= 1) v += __shfl_down(v, off);
  return v;
}

// ws layout: partial[q*NBLK + blk] (5*2048 floats = 40 KB), q:
//   0 = inter (sum p*t), 1 = sum_p, 2 = sum_t, 3 = attn sse, 4 = boundary (ungated)
// counter (1 uint) at byte offset 64 KB, zeroed by a 4-byte memset each call.
//
// Single kernel: per-row partials + last-block final reduce (saves the
// separate finalize dispatch). Exact EDT via outward early-exit search,
// batched 4 radii per memory round-trip:
//  - column distance: nearest fg / nearest bg in column x; once both found,
//    no farther pixel can improve the min -> break.
//  - row envelope: min over xp of g^2[xp] + (x-xp)^2; once r^2 >= running
//    min, all farther xp are dominated -> break. Degenerate rows/columns
//    fall through to the full scan, preserving exactness.
__global__ __launch_bounds__(256) void fused_kernel(
    const float* __restrict__ probs, const int* __restrict__ targets,
    const float* __restrict__ attn, float* __restrict__ partial,
    unsigned* __restrict__ counter, float* __restrict__ out) {
  const int blk = blockIdx.x;
  const int b = blk >> 8;
  const int y = blk & 255;
  const int x = threadIdx.x;
  const int tid = threadIdx.x;
  const int* __restrict__ timg = targets + b * HW_ELEMS;

  const int rowoff = b * HW_ELEMS + y * 256 + x;
  const float p = probs[rowoff];   // issued early; latency hides under phase 1
  const float a = attn[rowoff];
  const int t0 = timg[y * 256 + x];
  const float tf = (float)t0;

  // ---- phase 1: column distances (exact, early exit, batched loads) ----
  float dpos = t0 ? 0.f : BIGD;   // nearest fg in column x
  float dneg = t0 ? BIGD : 0.f;   // nearest bg in column x
  for (int r = 1; r < 256; r += 4) {
    if (dpos < BIGD && dneg < BIGD) break;
    int tu[4], td[4];
    #pragma unroll
    for (int j = 0; j < 4; ++j) {
      const int yu = y - (r + j), yd = y + (r + j);
      tu[j] = (yu >= 0)  ? timg[yu * 256 + x] : -1;
      td[j] = (yd < 256) ? timg[yd * 256 + x] : -1;
    }
    #pragma unroll
    for (int j = 0; j < 4; ++j) {
      const float fr = (float)(r + j);
      if (tu[j] == 1) dpos = fminf(dpos, fr); else if (tu[j] == 0) dneg = fminf(dneg, fr);
      if (td[j] == 1) dpos = fminf(dpos, fr); else if (td[j] == 0) dneg = fminf(dneg, fr);
    }
  }

  __shared__ float g2p[256], g2n[256];
  g2p[x] = dpos * dpos;
  g2n[x] = dneg * dneg;
  __syncthreads();

  // ---- phase 2: row lower envelope (exact, early exit, batched LDS) ----
  float m2p = g2p[x], m2n = g2n[x];
  for (int r = 1; r < 256; r += 4) {
    const float rr0 = (float)(r * r);
    if (rr0 >= m2p && rr0 >= m2n) break;
    #pragma unroll
    for (int j = 0; j < 4; ++j) {
      const int rj = r + j;
      const float rr = (float)(rj * rj);
      const int xl = x - rj, xr = x + rj;
      if (xl >= 0)  { m2p = fminf(m2p, rr + g2p[xl]); m2n = fminf(m2n, rr + g2n[xl]); }
      if (xr < 256) { m2p = fminf(m2p, rr + g2p[xr]); m2n = fminf(m2n, rr + g2n[xr]); }
    }
  }

  const float sdt = sqrtf(m2p) + sqrtf(m2n);
  const float contrib = p * sdt;           // any_fg gate applied in final reduce
  const float d = a - tf;

  // ---- fused row reductions ----
  const float v0 = waveSum(p * tf);
  const float v1 = waveSum(p);
  const float v2 = waveSum(tf);
  const float v3 = waveSum(d * d);
  const float v4 = waveSum(contrib);

  __shared__ float lds[4][5];
  const int wid = tid >> 6, lane = tid & 63;
  if (lane == 0) {
    lds[wid][0] = v0; lds[wid][1] = v1; lds[wid][2] = v2;
    lds[wid][3] = v3; lds[wid][4] = v4;
  }
  __syncthreads();
  if (tid == 0) {
    float s[5] = {0.f, 0.f, 0.f, 0.f, 0.f};
    #pragma unroll
    for (int w = 0; w < 4; ++w)
      #pragma unroll
      for (int q = 0; q < 5; ++q) s[q] += lds[w][q];
    #pragma unroll
    for (int q = 0; q < 5; ++q) partial[q * NBLK + blk] = s[q];  // plain stores
  }

  // ---- last-block final reduce (replaces the finalize dispatch) ----
  __shared__ unsigned isLastSh;
  if (tid == 0) {
    __threadfence();                       // release: partial stores visible device-wide
    const unsigned old = atomicAdd(counter, 1u);
    isLastSh = (old == NBLK - 1) ? 1u : 0u;
  }
  __syncthreads();
  if (isLastSh) {
    __threadfence();                       // acquire: order reads after the atomic
    __shared__ float red[32][8];
    __shared__ float sred[4];
    const int pair = tid >> 3, sub = tid & 7;     // 32 pairs x 8 subs
    const int qsel = pair >> 3;                    // 0..3 -> {inter, sum_p, sum_t, boundary}
    const int bb = pair & 7;
    const int qoff[4] = {0, 1, 2, 4};
    const int rbase = qoff[qsel] * NBLK + bb * 256 + sub * 32;
    float s = 0.f;
    #pragma unroll
    for (int j = 0; j < 32; ++j) s += partial[rbase + j];
    red[pair][sub] = s;

    float e = 0.f;                                // global sse (q=3)
    #pragma unroll
    for (int j = 0; j < 8; ++j) e += partial[3 * NBLK + tid * 8 + j];
    e = waveSum(e);
    if ((tid & 63) == 0) sred[tid >> 6] = e;
    __syncthreads();

    if (tid == 0) {
      float dsum = 0.f, tsum = 0.f, bsum = 0.f;
      for (int b2 = 0; b2 < 8; ++b2) {
        float inter = 0.f, sp = 0.f, st = 0.f, bd = 0.f;
        #pragma unroll
        for (int k = 0; k < 8; ++k) {
          inter += red[0 * 8 + b2][k];
          sp    += red[1 * 8 + b2][k];
          st    += red[2 * 8 + b2][k];
          bd    += red[3 * 8 + b2][k];
        }
        dsum += (2.f * inter + EPSL) / (sp + st + EPSL);
        const float fn = st - inter;
        const float fp = sp - inter;
        tsum += (inter + EPSL) / (inter + 0.3f * fn + 0.7f * fp + EPSL);
        bsum += (st > 0.5f) ? bd : 0.f;   // any_fg gate
      }
      const float sse = sred[0] + sred[1] + sred[2] + sred[3];
      const float dl = 1.f - dsum * 0.125f;
      const float tl = 1.f - tsum * 0.125f;
      const float bl = bsum * (1.f / 524288.f);
      const float al = sse * (1.f / 524288.f);
      out[0] = 1.0f * dl + 0.7f * tl + 0.5f * bl + 0.3f * al;
    }
  }
}

extern "C" void kernel_launch(void* const* d_in, const int* in_sizes, int n_in,
                              void* d_out, int out_size, void* d_ws, size_t ws_size,
                              hipStream_t stream) {
  const float* probs   = (const float*)d_in[0];
  const int*   targets = (const int*)d_in[1];
  const float* attn    = (const float*)d_in[2];
  float* out = (float*)d_out;
  float* partial = (float*)d_ws;                               // 40 KB
  unsigned* counter = (unsigned*)((char*)d_ws + 64 * 1024);    // 4 B, zero each call
  hipMemsetAsync(counter, 0, sizeof(unsigned), stream);
  fused_kernel<<<NBLK, 256, 0, stream>>>(probs, targets, attn, partial, counter, out);
}

// Round 11
// 71.422 us; speedup vs baseline: 1.5815x; 1.5815x over previous
//
#include <hip/hip_runtime.h>

// B=8, H=W=256, single channel. Output: one fp32 scalar (composite loss).
#define HW_ELEMS 65536
#define BIGD 1e4f
#define EPSL 1e-8f
#define NBLK 2048   // one block per (b, y) row

__device__ __forceinline__ float waveSum(float v) {
  #pragma unroll
  for (int off = 32; off > 0; off >>= 1) v += __shfl_down(v, off);
  return v;
}

// partial layout (SoA, floats): partial[q*NBLK + blk], q:
//   0 = inter (sum p*t), 1 = sum_p, 2 = sum_t, 3 = attn sse, 4 = boundary (ungated)
// NO atomics, NO device-scope fences (round-9 lesson: one __threadfence per
// block = L2 writeback per block on 8 non-coherent XCD L2s = +45 us).
// Each block writes its own 5 slots; the finalize dispatch boundary provides
// the cross-XCD visibility for free.
//
// One block per (b, y) row. Exact EDT via outward early-exit search, batched
// 4 radii per memory round-trip:
//  - column distance: nearest fg / nearest bg in column x; once both found,
//    no farther pixel can improve the min -> break.
//  - row envelope: min over xp of g^2[xp] + (x-xp)^2; once r^2 >= running
//    min, all farther xp are dominated -> break. Degenerate rows/columns
//    fall through to the full scan, preserving exactness.
__global__ __launch_bounds__(256) void fused_kernel(
    const float* __restrict__ probs, const int* __restrict__ targets,
    const float* __restrict__ attn, float* __restrict__ partial) {
  const int blk = blockIdx.x;
  const int b = blk >> 8;
  const int y = blk & 255;
  const int x = threadIdx.x;
  const int* __restrict__ timg = targets + b * HW_ELEMS;

  const int rowoff = b * HW_ELEMS + y * 256 + x;
  const float p = probs[rowoff];   // issued early; latency hides under phase 1
  const float a = attn[rowoff];
  const int t0 = timg[y * 256 + x];
  const float tf = (float)t0;

  // ---- phase 1: column distances (exact, early exit, batched loads) ----
  float dpos = t0 ? 0.f : BIGD;   // nearest fg in column x
  float dneg = t0 ? BIGD : 0.f;   // nearest bg in column x
  for (int r = 1; r < 256; r += 4) {
    if (dpos < BIGD && dneg < BIGD) break;
    int tu[4], td[4];
    #pragma unroll
    for (int j = 0; j < 4; ++j) {
      const int yu = y - (r + j), yd = y + (r + j);
      tu[j] = (yu >= 0)  ? timg[yu * 256 + x] : -1;
      td[j] = (yd < 256) ? timg[yd * 256 + x] : -1;
    }
    #pragma unroll
    for (int j = 0; j < 4; ++j) {
      const float fr = (float)(r + j);
      if (tu[j] == 1) dpos = fminf(dpos, fr); else if (tu[j] == 0) dneg = fminf(dneg, fr);
      if (td[j] == 1) dpos = fminf(dpos, fr); else if (td[j] == 0) dneg = fminf(dneg, fr);
    }
  }

  __shared__ float g2p[256], g2n[256];
  g2p[x] = dpos * dpos;
  g2n[x] = dneg * dneg;
  __syncthreads();

  // ---- phase 2: row lower envelope (exact, early exit, batched LDS) ----
  float m2p = g2p[x], m2n = g2n[x];
  for (int r = 1; r < 256; r += 4) {
    const float rr0 = (float)(r * r);
    if (rr0 >= m2p && rr0 >= m2n) break;
    #pragma unroll
    for (int j = 0; j < 4; ++j) {
      const int rj = r + j;
      const float rr = (float)(rj * rj);
      const int xl = x - rj, xr = x + rj;
      if (xl >= 0)  { m2p = fminf(m2p, rr + g2p[xl]); m2n = fminf(m2n, rr + g2n[xl]); }
      if (xr < 256) { m2p = fminf(m2p, rr + g2p[xr]); m2n = fminf(m2n, rr + g2n[xr]); }
    }
  }

  const float sdt = sqrtf(m2p) + sqrtf(m2n);
  const float contrib = p * sdt;           // any_fg gate applied in finalize
  const float d = a - tf;

  // ---- fused row reductions ----
  const float v0 = waveSum(p * tf);
  const float v1 = waveSum(p);
  const float v2 = waveSum(tf);
  const float v3 = waveSum(d * d);
  const float v4 = waveSum(contrib);

  __shared__ float lds[4][5];
  const int wid = threadIdx.x >> 6, lane = threadIdx.x & 63;
  if (lane == 0) {
    lds[wid][0] = v0; lds[wid][1] = v1; lds[wid][2] = v2;
    lds[wid][3] = v3; lds[wid][4] = v4;
  }
  __syncthreads();
  if (threadIdx.x == 0) {
    float s[5] = {0.f, 0.f, 0.f, 0.f, 0.f};
    #pragma unroll
    for (int w = 0; w < 4; ++w)
      #pragma unroll
      for (int q = 0; q < 5; ++q) s[q] += lds[w][q];
    #pragma unroll
    for (int q = 0; q < 5; ++q) partial[q * NBLK + blk] = s[q];  // plain stores
  }
}

// Single block, 256 threads: reduce 5*2048 partials, apply loss formula.
__global__ __launch_bounds__(256) void finalize_kernel(
    const float* __restrict__ partial, float* __restrict__ out) {
  const int tid = threadIdx.x;
  __shared__ float red[32][8];   // [qsel*8 + b][sub]
  __shared__ float sred[4];

  const int pair = tid >> 3, sub = tid & 7;     // 32 pairs x 8 subs
  const int qsel = pair >> 3;                    // 0..3
  const int bb = pair & 7;
  const int qoff[4] = {0, 1, 2, 4};
  const int base = qoff[qsel] * NBLK + bb * 256 + sub * 32;
  float s = 0.f;
  #pragma unroll
  for (int j = 0; j < 32; ++j) s += partial[base + j];
  red[pair][sub] = s;

  // global sse (q=3): 256 threads x 8 entries
  float e = 0.f;
  #pragma unroll
  for (int j = 0; j < 8; ++j) e += partial[3 * NBLK + tid * 8 + j];
  e = waveSum(e);
  if ((tid & 63) == 0) sred[tid >> 6] = e;
  __syncthreads();

  if (tid == 0) {
    float dsum = 0.f, tsum = 0.f, bsum = 0.f;
    for (int b2 = 0; b2 < 8; ++b2) {
      float inter = 0.f, sp = 0.f, st = 0.f, bd = 0.f;
      #pragma unroll
      for (int k = 0; k < 8; ++k) {
        inter += red[0 * 8 + b2][k];
        sp    += red[1 * 8 + b2][k];
        st    += red[2 * 8 + b2][k];
        bd    += red[3 * 8 + b2][k];
      }
      dsum += (2.f * inter + EPSL) / (sp + st + EPSL);
      const float fn = st - inter;
      const float fp = sp - inter;
      tsum += (inter + EPSL) / (inter + 0.3f * fn + 0.7f * fp + EPSL);
      bsum += (st > 0.5f) ? bd : 0.f;   // any_fg gate
    }
    const float sse = sred[0] + sred[1] + sred[2] + sred[3];
    const float dl = 1.f - dsum * 0.125f;
    const float tl = 1.f - tsum * 0.125f;
    const float bl = bsum * (1.f / 524288.f);
    const float al = sse * (1.f / 524288.f);
    out[0] = 1.0f * dl + 0.7f * tl + 0.5f * bl + 0.3f * al;
  }
}

extern "C" void kernel_launch(void* const* d_in, const int* in_sizes, int n_in,
                              void* d_out, int out_size, void* d_ws, size_t ws_size,
                              hipStream_t stream) {
  const float* probs   = (const float*)d_in[0];
  const int*   targets = (const int*)d_in[1];
  const float* attn    = (const float*)d_in[2];
  float* out = (float*)d_out;
  float* partial = (float*)d_ws;  // 5 * 2048 floats = 40 KB; fully written each call
  fused_kernel<<<NBLK, 256, 0, stream>>>(probs, targets, attn, partial);
  finalize_kernel<<<1, 256, 0, stream>>>(partial, out);
}